// Round 4
// baseline (680.668 us; speedup 1.0000x reference)
//
#include <hip/hip_runtime.h>

#define BATCH 16
#define CHN   512
#define INTER 64
#define NPIX  2304   // 48*48

typedef _Float16 f16;
typedef _Float16 f16x8 __attribute__((ext_vector_type(8)));
typedef _Float16 f16x4 __attribute__((ext_vector_type(4)));
typedef short    s16x8 __attribute__((ext_vector_type(8)));
typedef float    f32x16 __attribute__((ext_vector_type(16)));

// workspace byte offsets (total 85,590,016 B)
#define XT_OFF   ((size_t)0)          // xT f16  [b][n][c]   16*2304*512
#define QT_OFF   ((size_t)37748736)   // qT f16  [b][n][64]
#define KT_OFF   ((size_t)42467328)   // kT f16  [b][n][64]
#define VB_OFF   ((size_t)47185920)   // v  bf16 [b][c][m]   16*512*2304
#define WHQ_OFF  ((size_t)84934656)   // Wq f16  [64][512]
#define WHK_OFF  ((size_t)85000192)   // Wk f16  [64][512]
#define WHV_OFF  ((size_t)85065728)   // Wv f16  [512][512]

__device__ inline unsigned short f2bf(float f) {
    unsigned int u = __float_as_uint(f);
    unsigned int r = (u + 0x7FFFu + ((u >> 16) & 1u)) >> 16;
    return (unsigned short)r;
}

// pack two fp32 -> (bf16(a) | bf16(b)<<16), round-half-up via +0x8000 then v_perm
__device__ inline unsigned pack_bf16(float a, float b) {
    unsigned ua = __float_as_uint(a) + 0x8000u;
    unsigned ub = __float_as_uint(b) + 0x8000u;
    return __builtin_amdgcn_perm(ub, ua, 0x07060302u);
}

// Lane-half swap between two VGPRs: nx = [x.lo32lanes, y.lo32lanes],
// ny = [x.hi32lanes, y.hi32lanes].  gfx950 has a 1-instr primitive.
__device__ inline void swap32(unsigned x, unsigned y, unsigned& nx, unsigned& ny, int lh) {
#if __has_builtin(__builtin_amdgcn_permlane32_swap)
    auto r = __builtin_amdgcn_permlane32_swap(x, y, false, false);
    nx = r[0]; ny = r[1];
#else
    const unsigned xs = (unsigned)__shfl_xor((int)x, 32, 64);
    const unsigned ys = (unsigned)__shfl_xor((int)y, 32, 64);
    nx = lh ? ys : x;
    ny = lh ? y  : xs;
#endif
}

// ---------------------------------------------------------------------------
// x [b][c][n] fp32  ->  xT [b][n][c] f16   (64x64 LDS tile transpose)
// ---------------------------------------------------------------------------
__global__ __launch_bounds__(256) void convert_x_kernel(
    const float* __restrict__ x, f16* __restrict__ xT)
{
    const int n0 = blockIdx.x * 64;
    const int c0 = blockIdx.y * 64;
    const int b  = blockIdx.z;
    const int t  = threadIdx.x;

    __shared__ float tile[64][65];

    {
        const int cr   = t >> 2;
        const int ncol = (t & 3) * 16;
        const float* src = x + ((size_t)b * CHN + (size_t)(c0 + cr)) * NPIX + n0 + ncol;
        #pragma unroll
        for (int u = 0; u < 4; ++u) {
            const float4 v4 = *(const float4*)(src + u * 4);
            tile[cr][ncol + u * 4 + 0] = v4.x;
            tile[cr][ncol + u * 4 + 1] = v4.y;
            tile[cr][ncol + u * 4 + 2] = v4.z;
            tile[cr][ncol + u * 4 + 3] = v4.w;
        }
    }
    __syncthreads();
    #pragma unroll
    for (int r = 0; r < 2; ++r) {
        const int id = t + r * 256;
        const int n  = id >> 3;
        const int cg = id & 7;
        f16x8 o;
        #pragma unroll
        for (int j = 0; j < 8; ++j) o[j] = (f16)tile[cg * 8 + j][n];
        *(f16x8*)(xT + ((size_t)b * NPIX + (size_t)(n0 + n)) * CHN + c0 + cg * 8) = o;
    }
}

// ---------------------------------------------------------------------------
// W fp32 -> f16. grid (256, 3), block 256.
// ---------------------------------------------------------------------------
__global__ __launch_bounds__(256) void convert_w_kernel(
    const float* __restrict__ Wq, const float* __restrict__ Wk,
    const float* __restrict__ Wv, f16* __restrict__ whq,
    f16* __restrict__ whk, f16* __restrict__ whv)
{
    const int which = blockIdx.y;
    const float* src; f16* dst; int count;
    if (which == 0)      { src = Wq; dst = whq; count = 64 * 512; }
    else if (which == 1) { src = Wk; dst = whk; count = 64 * 512; }
    else                 { src = Wv; dst = whv; count = 512 * 512; }
    const int i = (blockIdx.x * 256 + threadIdx.x) * 4;
    if (i < count) {
        const float4 v4 = *(const float4*)(src + i);
        f16x4 o;
        o[0] = (f16)v4.x; o[1] = (f16)v4.y; o[2] = (f16)v4.z; o[3] = (f16)v4.w;
        *(f16x4*)(dst + i) = o;
    }
}

// ---------------------------------------------------------------------------
// Fused projection: virtual weight [Wq;Wk;Wv] (640 rows) x xT.
// grid (18 n-tiles(128), 5 row-tiles(128), 16 b), block 256.
// ---------------------------------------------------------------------------
__global__ __launch_bounds__(256, 2) void proj_kernel(
    const f16* __restrict__ xT, const f16* __restrict__ whq,
    const f16* __restrict__ whk, const f16* __restrict__ whv,
    f16* __restrict__ qTo, f16* __restrict__ kTo,
    unsigned short* __restrict__ vout)
{
    const int nt = blockIdx.x;
    const int rt = blockIdx.y;
    const int b  = blockIdx.z;
    const int t  = threadIdx.x;
    const int wave = t >> 6, lane = t & 63;
    const int row = lane & 31, lh = lane >> 5;

    __shared__ f16 wsm[128][72];
    __shared__ f16 xs[128][72];

    f32x16 acc[4];
    #pragma unroll
    for (int s = 0; s < 4; ++s)
        #pragma unroll
        for (int r = 0; r < 16; ++r) acc[s][r] = 0.0f;

    for (int c0 = 0; c0 < CHN; c0 += 64) {
        __syncthreads();
        #pragma unroll
        for (int r = 0; r < 4; ++r) {
            const int id = t + r * 256;     // 1024 8-elem chunks
            const int co = id >> 3, cg = id & 7;
            const f16* src;
            if (rt == 0) src = (co < 64) ? (whq + (size_t)co * CHN)
                                         : (whk + (size_t)(co - 64) * CHN);
            else         src = whv + (size_t)((rt - 1) * 128 + co) * CHN;
            *(f16x8*)&wsm[co][cg * 8] = *(const f16x8*)(src + c0 + cg * 8);
        }
        #pragma unroll
        for (int r = 0; r < 4; ++r) {
            const int id = t + r * 256;
            const int n = id >> 3, cg = id & 7;
            *(f16x8*)&xs[n][cg * 8] =
                *(const f16x8*)(xT + ((size_t)b * NPIX + (size_t)(nt * 128 + n)) * CHN + c0 + cg * 8);
        }
        __syncthreads();

        #pragma unroll
        for (int kk = 0; kk < 64; kk += 16) {
            const f16x8 bf = *(const f16x8*)&xs[wave * 32 + row][kk + lh * 8];
            #pragma unroll
            for (int cs = 0; cs < 4; ++cs) {
                const f16x8 af = *(const f16x8*)&wsm[cs * 32 + row][kk + lh * 8];
                acc[cs] = __builtin_amdgcn_mfma_f32_32x32x16_f16(af, bf, acc[cs], 0, 0, 0);
            }
        }
    }

    const int n = nt * 128 + wave * 32 + row;
    if (rt == 0) {
        #pragma unroll
        for (int cs = 0; cs < 4; ++cs)
            #pragma unroll
            for (int r = 0; r < 16; ++r) {
                const int i = cs * 32 + (r & 3) + 8 * (r >> 2) + 4 * lh;
                const f16 val = (f16)acc[cs][r];
                if (i < 64) qTo[((size_t)b * NPIX + n) * INTER + i] = val;
                else        kTo[((size_t)b * NPIX + n) * INTER + i - 64] = val;
            }
    } else {
        #pragma unroll
        for (int cs = 0; cs < 4; ++cs)
            #pragma unroll
            for (int r = 0; r < 16; ++r) {
                const int c = (rt - 1) * 128 + cs * 32 + (r & 3) + 8 * (r >> 2) + 4 * lh;
                vout[((size_t)b * CHN + c) * NPIX + n] = f2bf(acc[cs][r]);
            }
    }
}

// ---------------------------------------------------------------------------
// Attention — NO LDS, NO BARRIERS. Each wave is fully independent:
// wave = (n-half of the 64-q tile, 128-c range of the 256-c half).
// Per 64-m tile: QK^T for BOTH m-halves of this wave's 32 n (8 MFMA, the 2x
// QK redundancy buys zero cross-wave deps) -> exp (unnormalized, fp32-range
// safe in bf16) -> pack pairs -> 8 lane-half swaps convert D-layout P to
// B-operand layout in registers -> PV (16 MFMA, v A-frags direct from global).
// l accumulated per-lane; l[n] = lane + lane^32 via one shfl at the end.
// grid (36 n-tiles, 2 c-halves, 16 b), block 256 (4 waves).
// ---------------------------------------------------------------------------
__global__ __launch_bounds__(256, 2) void attn_kernel(
    const float* __restrict__ x, const float* __restrict__ gamma,
    const f16* __restrict__ qT, const f16* __restrict__ kT,
    const unsigned short* __restrict__ vhalfbase, float* __restrict__ out)
{
    const int nt  = blockIdx.x;
    const int chh = blockIdx.y;
    const int b   = blockIdx.z;
    const int t   = threadIdx.x;
    const int wave = t >> 6, lane = t & 63;
    const int row = lane & 31, lh = lane >> 5;
    const int h  = wave & 1;      // n-half (32 queries)
    const int cr = wave >> 1;     // c-range (128 channels of this 256-half)
    const int n0w = nt * 64 + h * 32;

    const unsigned short* v = vhalfbase + ((size_t)b * CHN + (size_t)chh * 256) * NPIX;
    const unsigned short* vrow = v + (size_t)(cr * 128 + row) * NPIX + lh * 8;
    const f16* qrow = qT + ((size_t)b * NPIX + (size_t)(n0w + row)) * INTER + lh * 8;
    const f16* krow = kT + ((size_t)b * NPIX + (size_t)row) * INTER + lh * 8;

    // q fragments: resident for whole kernel (B operand: col n = row)
    f16x8 qf[4];
    #pragma unroll
    for (int k0 = 0; k0 < 4; ++k0) qf[k0] = *(const f16x8*)(qrow + k0 * 16);

    f32x16 accv[4];
    #pragma unroll
    for (int s = 0; s < 4; ++s)
        #pragma unroll
        for (int r = 0; r < 16; ++r) accv[s][r] = 0.0f;

    float lrun = 0.0f;

    union PB { unsigned u[4]; s16x8 v; };

    for (int it = 0; it < NPIX / 64; ++it) {
        const int m0 = it * 64;

        // ---- k fragments first (QK waits only on these), then v fragments
        f16x8 kf[2][4];
        #pragma unroll
        for (int mh = 0; mh < 2; ++mh)
            #pragma unroll
            for (int k0 = 0; k0 < 4; ++k0)
                kf[mh][k0] = *(const f16x8*)(krow + (size_t)(m0 + mh * 32) * INTER + k0 * 16);

        s16x8 va[4][4];
        #pragma unroll
        for (int cs = 0; cs < 4; ++cs)
            #pragma unroll
            for (int kk = 0; kk < 4; ++kk)
                va[cs][kk] = *(const s16x8*)(vrow + (size_t)(cs * 32) * NPIX + m0 + kk * 16);

        // ---- QK^T both m-halves for this wave's 32 n; exp + pack
        unsigned pg[2][8];   // [mh][2g+p]: bf16 pair (m = mh*32+8g+2p+4lh +{0,1})
        float lp = 0.0f;
        #pragma unroll
        for (int mh = 0; mh < 2; ++mh) {
            f32x16 sacc;
            #pragma unroll
            for (int r = 0; r < 16; ++r) sacc[r] = 0.0f;
            #pragma unroll
            for (int k0 = 0; k0 < 4; ++k0)
                sacc = __builtin_amdgcn_mfma_f32_32x32x16_f16(kf[mh][k0], qf[k0], sacc, 0, 0, 0);
            #pragma unroll
            for (int tt = 0; tt < 8; ++tt) {
                const float p0 = __expf(sacc[2 * tt + 0]);
                const float p1 = __expf(sacc[2 * tt + 1]);
                lp += p0 + p1;
                pg[mh][tt] = pack_bf16(p0, p1);
            }
        }
        lrun += lp;

        // ---- D-layout -> B-operand layout via lane-half swaps (in-register)
        PB B[4];
        #pragma unroll
        for (int mh = 0; mh < 2; ++mh)
            #pragma unroll
            for (int half = 0; half < 2; ++half)
                #pragma unroll
                for (int p = 0; p < 2; ++p) {
                    unsigned nx, ny;
                    swap32(pg[mh][half * 4 + p], pg[mh][half * 4 + 2 + p], nx, ny, lh);
                    B[2 * mh + half].u[p]     = nx;
                    B[2 * mh + half].u[p + 2] = ny;
                }

        // ---- PV: accv[cs] covers (32 c) x (this wave's 32 n)
        #pragma unroll
        for (int cs = 0; cs < 4; ++cs)
            #pragma unroll
            for (int kk = 0; kk < 4; ++kk)
                accv[cs] = __builtin_amdgcn_mfma_f32_32x32x16_bf16(
                    va[cs][kk], B[kk].v, accv[cs], 0, 0, 0);
    }

    // ---- l combine (lane + partner lane covers all m), epilogue
    const float ltot = lrun + __shfl_xor(lrun, 32, 64);
    const float linv = 1.0f / ltot;
    const float g = gamma[0];
    const int n = n0w + row;
    #pragma unroll
    for (int cs = 0; cs < 4; ++cs)
        #pragma unroll
        for (int r = 0; r < 16; ++r) {
            const int c = chh * 256 + cr * 128 + cs * 32 + (r & 3) + 8 * (r >> 2) + 4 * lh;
            const size_t idx = ((size_t)b * CHN + c) * NPIX + n;
            out[idx] = g * accv[cs][r] * linv + x[idx];
        }
}

// ---------------------------------------------------------------------------
extern "C" void kernel_launch(void* const* d_in, const int* in_sizes, int n_in,
                              void* d_out, int out_size, void* d_ws, size_t ws_size,
                              hipStream_t stream) {
    (void)in_sizes; (void)n_in; (void)out_size; (void)ws_size;
    const float* x     = (const float*)d_in[0];
    const float* Wq    = (const float*)d_in[1];
    const float* Wk    = (const float*)d_in[2];
    const float* Wv    = (const float*)d_in[3];
    const float* gamma = (const float*)d_in[4];
    float* out = (float*)d_out;
    char* ws = (char*)d_ws;

    f16* xT  = (f16*)(ws + XT_OFF);
    f16* qTp = (f16*)(ws + QT_OFF);
    f16* kTp = (f16*)(ws + KT_OFF);
    unsigned short* vb = (unsigned short*)(ws + VB_OFF);
    f16* whq = (f16*)(ws + WHQ_OFF);
    f16* whk = (f16*)(ws + WHK_OFF);
    f16* whv = (f16*)(ws + WHV_OFF);

    convert_x_kernel<<<dim3(36, 8, 16), 256, 0, stream>>>(x, xT);
    convert_w_kernel<<<dim3(256, 3, 1), 256, 0, stream>>>(Wq, Wk, Wv, whq, whk, whv);
    proj_kernel<<<dim3(18, 5, 16), 256, 0, stream>>>(xT, whq, whk, whv, qTp, kTp, vb);
    attn_kernel<<<dim3(36, 2, 16), 256, 0, stream>>>(x, gamma, qTp, kTp, vb, out);
}

// Round 5
// 485.797 us; speedup vs baseline: 1.4011x; 1.4011x over previous
//
#include <hip/hip_runtime.h>

#define BATCH 16
#define CHN   512
#define INTER 64
#define NPIX  2304   // 48*48

typedef _Float16 f16;
typedef _Float16 f16x8 __attribute__((ext_vector_type(8)));
typedef _Float16 f16x4 __attribute__((ext_vector_type(4)));
typedef short    s16x8 __attribute__((ext_vector_type(8)));
typedef float    f32x16 __attribute__((ext_vector_type(16)));

// workspace byte offsets (total 85,590,016 B)
#define XT_OFF   ((size_t)0)          // xT f16  [b][n][c]   16*2304*512
#define QT_OFF   ((size_t)37748736)   // qT f16  [b][n][64]
#define KT_OFF   ((size_t)42467328)   // kT f16  [b][n][64]
#define VB_OFF   ((size_t)47185920)   // v  bf16 [b][c][m]   16*512*2304
#define WHQ_OFF  ((size_t)84934656)   // Wq f16  [64][512]
#define WHK_OFF  ((size_t)85000192)   // Wk f16  [64][512]
#define WHV_OFF  ((size_t)85065728)   // Wv f16  [512][512]

__device__ inline unsigned short f2bf(float f) {
    unsigned int u = __float_as_uint(f);
    unsigned int r = (u + 0x7FFFu + ((u >> 16) & 1u)) >> 16;
    return (unsigned short)r;
}

// pack two fp32 -> (bf16(a) | bf16(b)<<16), round-half-up via +0x8000 then v_perm
__device__ inline unsigned pack_bf16(float a, float b) {
    unsigned ua = __float_as_uint(a) + 0x8000u;
    unsigned ub = __float_as_uint(b) + 0x8000u;
    return __builtin_amdgcn_perm(ub, ua, 0x07060302u);
}

// Lane-half swap between two VGPRs (HW-verified correct in round 4).
__device__ inline void swap32(unsigned x, unsigned y, unsigned& nx, unsigned& ny, int lh) {
#if __has_builtin(__builtin_amdgcn_permlane32_swap)
    auto r = __builtin_amdgcn_permlane32_swap(x, y, false, false);
    nx = r[0]; ny = r[1];
#else
    const unsigned xs = (unsigned)__shfl_xor((int)x, 32, 64);
    const unsigned ys = (unsigned)__shfl_xor((int)y, 32, 64);
    nx = lh ? ys : x;
    ny = lh ? y  : xs;
#endif
}

// ---------------------------------------------------------------------------
// x [b][c][n] fp32  ->  xT [b][n][c] f16   (64x64 LDS tile transpose)
// ---------------------------------------------------------------------------
__global__ __launch_bounds__(256) void convert_x_kernel(
    const float* __restrict__ x, f16* __restrict__ xT)
{
    const int n0 = blockIdx.x * 64;
    const int c0 = blockIdx.y * 64;
    const int b  = blockIdx.z;
    const int t  = threadIdx.x;

    __shared__ float tile[64][65];

    {
        const int cr   = t >> 2;
        const int ncol = (t & 3) * 16;
        const float* src = x + ((size_t)b * CHN + (size_t)(c0 + cr)) * NPIX + n0 + ncol;
        #pragma unroll
        for (int u = 0; u < 4; ++u) {
            const float4 v4 = *(const float4*)(src + u * 4);
            tile[cr][ncol + u * 4 + 0] = v4.x;
            tile[cr][ncol + u * 4 + 1] = v4.y;
            tile[cr][ncol + u * 4 + 2] = v4.z;
            tile[cr][ncol + u * 4 + 3] = v4.w;
        }
    }
    __syncthreads();
    #pragma unroll
    for (int r = 0; r < 2; ++r) {
        const int id = t + r * 256;
        const int n  = id >> 3;
        const int cg = id & 7;
        f16x8 o;
        #pragma unroll
        for (int j = 0; j < 8; ++j) o[j] = (f16)tile[cg * 8 + j][n];
        *(f16x8*)(xT + ((size_t)b * NPIX + (size_t)(n0 + n)) * CHN + c0 + cg * 8) = o;
    }
}

// ---------------------------------------------------------------------------
// W fp32 -> f16. grid (256, 3), block 256.
// ---------------------------------------------------------------------------
__global__ __launch_bounds__(256) void convert_w_kernel(
    const float* __restrict__ Wq, const float* __restrict__ Wk,
    const float* __restrict__ Wv, f16* __restrict__ whq,
    f16* __restrict__ whk, f16* __restrict__ whv)
{
    const int which = blockIdx.y;
    const float* src; f16* dst; int count;
    if (which == 0)      { src = Wq; dst = whq; count = 64 * 512; }
    else if (which == 1) { src = Wk; dst = whk; count = 64 * 512; }
    else                 { src = Wv; dst = whv; count = 512 * 512; }
    const int i = (blockIdx.x * 256 + threadIdx.x) * 4;
    if (i < count) {
        const float4 v4 = *(const float4*)(src + i);
        f16x4 o;
        o[0] = (f16)v4.x; o[1] = (f16)v4.y; o[2] = (f16)v4.z; o[3] = (f16)v4.w;
        *(f16x4*)(dst + i) = o;
    }
}

// ---------------------------------------------------------------------------
// Fused projection: virtual weight [Wq;Wk;Wv] (640 rows) x xT.
// grid (18 n-tiles(128), 5 row-tiles(128), 16 b), block 256.
// ---------------------------------------------------------------------------
__global__ __launch_bounds__(256, 2) void proj_kernel(
    const f16* __restrict__ xT, const f16* __restrict__ whq,
    const f16* __restrict__ whk, const f16* __restrict__ whv,
    f16* __restrict__ qTo, f16* __restrict__ kTo,
    unsigned short* __restrict__ vout)
{
    const int nt = blockIdx.x;
    const int rt = blockIdx.y;
    const int b  = blockIdx.z;
    const int t  = threadIdx.x;
    const int wave = t >> 6, lane = t & 63;
    const int row = lane & 31, lh = lane >> 5;

    __shared__ f16 wsm[128][72];
    __shared__ f16 xs[128][72];

    f32x16 acc[4];
    #pragma unroll
    for (int s = 0; s < 4; ++s)
        #pragma unroll
        for (int r = 0; r < 16; ++r) acc[s][r] = 0.0f;

    for (int c0 = 0; c0 < CHN; c0 += 64) {
        __syncthreads();
        #pragma unroll
        for (int r = 0; r < 4; ++r) {
            const int id = t + r * 256;     // 1024 8-elem chunks
            const int co = id >> 3, cg = id & 7;
            const f16* src;
            if (rt == 0) src = (co < 64) ? (whq + (size_t)co * CHN)
                                         : (whk + (size_t)(co - 64) * CHN);
            else         src = whv + (size_t)((rt - 1) * 128 + co) * CHN;
            *(f16x8*)&wsm[co][cg * 8] = *(const f16x8*)(src + c0 + cg * 8);
        }
        #pragma unroll
        for (int r = 0; r < 4; ++r) {
            const int id = t + r * 256;
            const int n = id >> 3, cg = id & 7;
            *(f16x8*)&xs[n][cg * 8] =
                *(const f16x8*)(xT + ((size_t)b * NPIX + (size_t)(nt * 128 + n)) * CHN + c0 + cg * 8);
        }
        __syncthreads();

        #pragma unroll
        for (int kk = 0; kk < 64; kk += 16) {
            const f16x8 bf = *(const f16x8*)&xs[wave * 32 + row][kk + lh * 8];
            #pragma unroll
            for (int cs = 0; cs < 4; ++cs) {
                const f16x8 af = *(const f16x8*)&wsm[cs * 32 + row][kk + lh * 8];
                acc[cs] = __builtin_amdgcn_mfma_f32_32x32x16_f16(af, bf, acc[cs], 0, 0, 0);
            }
        }
    }

    const int n = nt * 128 + wave * 32 + row;
    if (rt == 0) {
        #pragma unroll
        for (int cs = 0; cs < 4; ++cs)
            #pragma unroll
            for (int r = 0; r < 16; ++r) {
                const int i = cs * 32 + (r & 3) + 8 * (r >> 2) + 4 * lh;
                const f16 val = (f16)acc[cs][r];
                if (i < 64) qTo[((size_t)b * NPIX + n) * INTER + i] = val;
                else        kTo[((size_t)b * NPIX + n) * INTER + i - 64] = val;
            }
    } else {
        #pragma unroll
        for (int cs = 0; cs < 4; ++cs)
            #pragma unroll
            for (int r = 0; r < 16; ++r) {
                const int c = (rt - 1) * 128 + cs * 32 + (r & 3) + 8 * (r >> 2) + 4 * lh;
                vout[((size_t)b * CHN + c) * NPIX + n] = f2bf(acc[cs][r]);
            }
    }
}

// ---------------------------------------------------------------------------
// Attention v5: ALL in-loop global reads coalesced; fragments from LDS.
// Block = 128 n x 128 c, 4 waves: wave = (nw = n-half, cw = c-half).
// Per 64-m tile (double-buffered LDS, ONE barrier/iter):
//   - stage v-tile (128c x 64m bf16, 16 KB) + k-tile (64m x 64i f16, 8 KB)
//     with fully-coalesced 16B loads; LDS layout chunk-XOR-swizzled so both
//     writes and b128 fragment reads are <=2-way bank aliased (free).
//   - QK^T for this wave's 64 n, both m-halves (f16 MFMA, A=k from LDS,
//     B=q regs; 2x redundancy buys zero cross-wave P dependency)
//   - exp (unnormalized; bf16 carries fp32 exponent range) -> pack -> in-reg
//     permlane32 swaps (HW-verified in R4) -> PV B-operands
//   - PV (bf16 MFMA, A=v from LDS)
// grid (18 n-tiles, 4 c-quarters, 16 b) = 1152 blocks, block 256.
// ---------------------------------------------------------------------------
__global__ __launch_bounds__(256, 2) void attn_kernel(
    const float* __restrict__ x, const float* __restrict__ gamma,
    const f16* __restrict__ qT, const f16* __restrict__ kT,
    const unsigned short* __restrict__ vglob, float* __restrict__ out)
{
    const int nt = blockIdx.x;    // 128-n tile
    const int cq = blockIdx.y;    // 128-c quarter
    const int b  = blockIdx.z;
    const int t  = threadIdx.x;
    const int wave = t >> 6, lane = t & 63;
    const int row = lane & 31, lh = lane >> 5;
    const int cw = wave & 1;      // c-half (64 c) within the 128-c quarter
    const int nw = wave >> 1;     // n-half (64 n) within the 128-n tile

    __shared__ short vbuf[2][128 * 64];   // [buf][c][m] chunk-swizzled, 32 KB
    __shared__ f16   kbuf[2][64 * 64];    // [buf][m][i] chunk-swizzled, 16 KB

    const unsigned short* vq = vglob + ((size_t)b * CHN + (size_t)cq * 128) * NPIX;
    const f16* kb = kT + (size_t)b * NPIX * INTER;

    // staging ids (coalesced global: inner 8 chunks = one 128 B row)
    const int vcr = t >> 3;        // base v c-row (0..31), +32*j
    const int vmc = t & 7;         // m-chunk
    const int kmm = t >> 3;        // base k m-row
    const int kic = t & 7;         // i-chunk

    // fragment read offsets (xor = row&7; +32 row shifts keep it)
    const int xorv = row & 7;

    // q fragments: resident (B operand; col n = lane&31)
    f16x8 qf[2][4];
    #pragma unroll
    for (int ns = 0; ns < 2; ++ns) {
        const f16* qrow = qT + ((size_t)b * NPIX + (size_t)(nt * 128 + nw * 64 + ns * 32 + row)) * INTER + lh * 8;
        #pragma unroll
        for (int k0 = 0; k0 < 4; ++k0) qf[ns][k0] = *(const f16x8*)(qrow + k0 * 16);
    }

    // ---- prologue: stage tile 0 into buf 0
    #pragma unroll
    for (int j = 0; j < 4; ++j) {
        const int cr = vcr + j * 32;
        const s16x8 g = *(const s16x8*)(vq + (size_t)cr * NPIX + vmc * 8);
        *(s16x8*)&vbuf[0][cr * 64 + ((vmc ^ (cr & 7)) * 8)] = g;
    }
    #pragma unroll
    for (int j = 0; j < 2; ++j) {
        const int mm = kmm + j * 32;
        const f16x8 g = *(const f16x8*)(kb + (size_t)mm * INTER + kic * 8);
        *(f16x8*)&kbuf[0][mm * 64 + ((kic ^ (mm & 7)) * 8)] = g;
    }
    __syncthreads();

    f32x16 accv[4];   // [cs*2+ns]
    #pragma unroll
    for (int s = 0; s < 4; ++s)
        #pragma unroll
        for (int r = 0; r < 16; ++r) accv[s][r] = 0.0f;

    float lrun[2] = {0.0f, 0.0f};
    union PB { unsigned u[4]; s16x8 v; };

    for (int it = 0; it < NPIX / 64; ++it) {
        const int cur = it & 1, nxt = cur ^ 1;
        const int m1 = (it < NPIX / 64 - 1) ? (it + 1) * 64 : 0;  // last: dummy reload

        // ---- issue coalesced global loads for tile it+1 (latency spans QK+exp)
        s16x8 vg[4]; f16x8 kg[2];
        #pragma unroll
        for (int j = 0; j < 4; ++j)
            vg[j] = *(const s16x8*)(vq + (size_t)(vcr + j * 32) * NPIX + m1 + vmc * 8);
        #pragma unroll
        for (int j = 0; j < 2; ++j)
            kg[j] = *(const f16x8*)(kb + (size_t)(m1 + kmm + j * 32) * INTER + kic * 8);

        // ---- QK^T (A = k-frags from LDS, B = q regs) + exp + in-reg transform
        PB pb[2][4];   // [ns][kk]
        #pragma unroll
        for (int ns = 0; ns < 2; ++ns) {
            #pragma unroll
            for (int mh = 0; mh < 2; ++mh) {
                f32x16 sacc;
                #pragma unroll
                for (int r = 0; r < 16; ++r) sacc[r] = 0.0f;
                #pragma unroll
                for (int k0 = 0; k0 < 4; ++k0) {
                    const f16x8 af = *(const f16x8*)&kbuf[cur][(mh * 32 + row) * 64
                                        + (((k0 * 2 + lh) ^ xorv) * 8)];
                    sacc = __builtin_amdgcn_mfma_f32_32x32x16_f16(af, qf[ns][k0], sacc, 0, 0, 0);
                }
                float lp = 0.0f;
                unsigned pg[8];
                #pragma unroll
                for (int tt = 0; tt < 8; ++tt) {
                    const float p0 = __expf(sacc[2 * tt + 0]);
                    const float p1 = __expf(sacc[2 * tt + 1]);
                    lp += p0 + p1;
                    pg[tt] = pack_bf16(p0, p1);
                }
                lrun[ns] += lp;
                #pragma unroll
                for (int half = 0; half < 2; ++half)
                    #pragma unroll
                    for (int p = 0; p < 2; ++p) {
                        unsigned nx, ny;
                        swap32(pg[half * 4 + p], pg[half * 4 + 2 + p], nx, ny, lh);
                        pb[ns][2 * mh + half].u[p]     = nx;
                        pb[ns][2 * mh + half].u[p + 2] = ny;
                    }
            }
        }

        // ---- write staged tile it+1 into alt buffers (vmcnt drained here)
        #pragma unroll
        for (int j = 0; j < 4; ++j) {
            const int cr = vcr + j * 32;
            *(s16x8*)&vbuf[nxt][cr * 64 + ((vmc ^ (cr & 7)) * 8)] = vg[j];
        }
        #pragma unroll
        for (int j = 0; j < 2; ++j) {
            const int mm = kmm + j * 32;
            *(f16x8*)&kbuf[nxt][mm * 64 + ((kic ^ (mm & 7)) * 8)] = kg[j];
        }

        // ---- PV: A = v-frags from LDS, B = pb regs
        #pragma unroll
        for (int cs = 0; cs < 2; ++cs)
            #pragma unroll
            for (int kk = 0; kk < 4; ++kk) {
                const s16x8 va = *(const s16x8*)&vbuf[cur][(cw * 64 + cs * 32 + row) * 64
                                    + (((kk * 2 + lh) ^ xorv) * 8)];
                #pragma unroll
                for (int ns = 0; ns < 2; ++ns)
                    accv[cs * 2 + ns] = __builtin_amdgcn_mfma_f32_32x32x16_bf16(
                        va, pb[ns][kk].v, accv[cs * 2 + ns], 0, 0, 0);
            }

        __syncthreads();   // cur-buf readers done; nxt-buf writes visible
    }

    // ---- epilogue: l combine (lane-half pair), out = g*acc/l + x
    const float g = gamma[0];
    float linv[2];
    #pragma unroll
    for (int ns = 0; ns < 2; ++ns)
        linv[ns] = 1.0f / (lrun[ns] + __shfl_xor(lrun[ns], 32, 64));

    #pragma unroll
    for (int cs = 0; cs < 2; ++cs)
        #pragma unroll
        for (int ns = 0; ns < 2; ++ns)
            #pragma unroll
            for (int r = 0; r < 16; ++r) {
                const int c = cq * 128 + cw * 64 + cs * 32 + (r & 3) + 8 * (r >> 2) + 4 * lh;
                const int n = nt * 128 + nw * 64 + ns * 32 + row;
                const size_t idx = ((size_t)b * CHN + c) * NPIX + n;
                out[idx] = g * accv[cs * 2 + ns][r] * linv[ns] + x[idx];
            }
}

// ---------------------------------------------------------------------------
extern "C" void kernel_launch(void* const* d_in, const int* in_sizes, int n_in,
                              void* d_out, int out_size, void* d_ws, size_t ws_size,
                              hipStream_t stream) {
    (void)in_sizes; (void)n_in; (void)out_size; (void)ws_size;
    const float* x     = (const float*)d_in[0];
    const float* Wq    = (const float*)d_in[1];
    const float* Wk    = (const float*)d_in[2];
    const float* Wv    = (const float*)d_in[3];
    const float* gamma = (const float*)d_in[4];
    float* out = (float*)d_out;
    char* ws = (char*)d_ws;

    f16* xT  = (f16*)(ws + XT_OFF);
    f16* qTp = (f16*)(ws + QT_OFF);
    f16* kTp = (f16*)(ws + KT_OFF);
    unsigned short* vb = (unsigned short*)(ws + VB_OFF);
    f16* whq = (f16*)(ws + WHQ_OFF);
    f16* whk = (f16*)(ws + WHK_OFF);
    f16* whv = (f16*)(ws + WHV_OFF);

    convert_x_kernel<<<dim3(36, 8, 16), 256, 0, stream>>>(x, xT);
    convert_w_kernel<<<dim3(256, 3, 1), 256, 0, stream>>>(Wq, Wk, Wv, whq, whk, whv);
    proj_kernel<<<dim3(18, 5, 16), 256, 0, stream>>>(xT, whq, whk, whv, qTp, kTp, vb);
    attn_kernel<<<dim3(18, 4, 16), 256, 0, stream>>>(x, gamma, qTp, kTp, vb, out);
}

// Round 6
// 377.745 us; speedup vs baseline: 1.8019x; 1.2860x over previous
//
#include <hip/hip_runtime.h>

#define BATCH 16
#define CHN   512
#define INTER 64
#define NPIX  2304   // 48*48

typedef _Float16 f16;
typedef _Float16 f16x8 __attribute__((ext_vector_type(8)));
typedef _Float16 f16x4 __attribute__((ext_vector_type(4)));
typedef short    s16x8 __attribute__((ext_vector_type(8)));
typedef float    f32x16 __attribute__((ext_vector_type(16)));

// workspace byte offsets (total 85,590,016 B)
#define XT_OFF   ((size_t)0)          // xT f16  [b][n][c]   16*2304*512
#define QT_OFF   ((size_t)37748736)   // qT f16  [b][n][64]
#define KT_OFF   ((size_t)42467328)   // kT f16  [b][n][64]
#define VB_OFF   ((size_t)47185920)   // v  bf16 [b][c][m]   16*512*2304
#define WHQ_OFF  ((size_t)84934656)   // Wq f16  [64][512]
#define WHK_OFF  ((size_t)85000192)   // Wk f16  [64][512]
#define WHV_OFF  ((size_t)85065728)   // Wv f16  [512][512]

__device__ inline unsigned short f2bf(float f) {
    unsigned int u = __float_as_uint(f);
    unsigned int r = (u + 0x7FFFu + ((u >> 16) & 1u)) >> 16;
    return (unsigned short)r;
}

// pack two fp32 -> (bf16(a) | bf16(b)<<16), round-half-up via +0x8000 then v_perm
__device__ inline unsigned pack_bf16(float a, float b) {
    unsigned ua = __float_as_uint(a) + 0x8000u;
    unsigned ub = __float_as_uint(b) + 0x8000u;
    return __builtin_amdgcn_perm(ub, ua, 0x07060302u);
}

// Lane-half swap between two VGPRs (HW-verified correct in rounds 4/5).
__device__ inline void swap32(unsigned x, unsigned y, unsigned& nx, unsigned& ny, int lh) {
#if __has_builtin(__builtin_amdgcn_permlane32_swap)
    auto r = __builtin_amdgcn_permlane32_swap(x, y, false, false);
    nx = r[0]; ny = r[1];
#else
    const unsigned xs = (unsigned)__shfl_xor((int)x, 32, 64);
    const unsigned ys = (unsigned)__shfl_xor((int)y, 32, 64);
    nx = lh ? ys : x;
    ny = lh ? y  : xs;
#endif
}

// ---------------------------------------------------------------------------
// x [b][c][n] fp32  ->  xT [b][n][c] f16   (64x64 LDS tile transpose)
// ---------------------------------------------------------------------------
__global__ __launch_bounds__(256) void convert_x_kernel(
    const float* __restrict__ x, f16* __restrict__ xT)
{
    const int n0 = blockIdx.x * 64;
    const int c0 = blockIdx.y * 64;
    const int b  = blockIdx.z;
    const int t  = threadIdx.x;

    __shared__ float tile[64][65];

    {
        const int cr   = t >> 2;
        const int ncol = (t & 3) * 16;
        const float* src = x + ((size_t)b * CHN + (size_t)(c0 + cr)) * NPIX + n0 + ncol;
        #pragma unroll
        for (int u = 0; u < 4; ++u) {
            const float4 v4 = *(const float4*)(src + u * 4);
            tile[cr][ncol + u * 4 + 0] = v4.x;
            tile[cr][ncol + u * 4 + 1] = v4.y;
            tile[cr][ncol + u * 4 + 2] = v4.z;
            tile[cr][ncol + u * 4 + 3] = v4.w;
        }
    }
    __syncthreads();
    #pragma unroll
    for (int r = 0; r < 2; ++r) {
        const int id = t + r * 256;
        const int n  = id >> 3;
        const int cg = id & 7;
        f16x8 o;
        #pragma unroll
        for (int j = 0; j < 8; ++j) o[j] = (f16)tile[cg * 8 + j][n];
        *(f16x8*)(xT + ((size_t)b * NPIX + (size_t)(n0 + n)) * CHN + c0 + cg * 8) = o;
    }
}

// ---------------------------------------------------------------------------
// W fp32 -> f16. grid (256, 3), block 256.
// ---------------------------------------------------------------------------
__global__ __launch_bounds__(256) void convert_w_kernel(
    const float* __restrict__ Wq, const float* __restrict__ Wk,
    const float* __restrict__ Wv, f16* __restrict__ whq,
    f16* __restrict__ whk, f16* __restrict__ whv)
{
    const int which = blockIdx.y;
    const float* src; f16* dst; int count;
    if (which == 0)      { src = Wq; dst = whq; count = 64 * 512; }
    else if (which == 1) { src = Wk; dst = whk; count = 64 * 512; }
    else                 { src = Wv; dst = whv; count = 512 * 512; }
    const int i = (blockIdx.x * 256 + threadIdx.x) * 4;
    if (i < count) {
        const float4 v4 = *(const float4*)(src + i);
        f16x4 o;
        o[0] = (f16)v4.x; o[1] = (f16)v4.y; o[2] = (f16)v4.z; o[3] = (f16)v4.w;
        *(f16x4*)(dst + i) = o;
    }
}

// ---------------------------------------------------------------------------
// Fused projection: virtual weight [Wq;Wk;Wv] (640 rows) x xT.
// grid (18 n-tiles(128), 5 row-tiles(128), 16 b), block 256.
// ---------------------------------------------------------------------------
__global__ __launch_bounds__(256, 2) void proj_kernel(
    const f16* __restrict__ xT, const f16* __restrict__ whq,
    const f16* __restrict__ whk, const f16* __restrict__ whv,
    f16* __restrict__ qTo, f16* __restrict__ kTo,
    unsigned short* __restrict__ vout)
{
    const int nt = blockIdx.x;
    const int rt = blockIdx.y;
    const int b  = blockIdx.z;
    const int t  = threadIdx.x;
    const int wave = t >> 6, lane = t & 63;
    const int row = lane & 31, lh = lane >> 5;

    __shared__ f16 wsm[128][72];
    __shared__ f16 xs[128][72];

    f32x16 acc[4];
    #pragma unroll
    for (int s = 0; s < 4; ++s)
        #pragma unroll
        for (int r = 0; r < 16; ++r) acc[s][r] = 0.0f;

    for (int c0 = 0; c0 < CHN; c0 += 64) {
        __syncthreads();
        #pragma unroll
        for (int r = 0; r < 4; ++r) {
            const int id = t + r * 256;     // 1024 8-elem chunks
            const int co = id >> 3, cg = id & 7;
            const f16* src;
            if (rt == 0) src = (co < 64) ? (whq + (size_t)co * CHN)
                                         : (whk + (size_t)(co - 64) * CHN);
            else         src = whv + (size_t)((rt - 1) * 128 + co) * CHN;
            *(f16x8*)&wsm[co][cg * 8] = *(const f16x8*)(src + c0 + cg * 8);
        }
        #pragma unroll
        for (int r = 0; r < 4; ++r) {
            const int id = t + r * 256;
            const int n = id >> 3, cg = id & 7;
            *(f16x8*)&xs[n][cg * 8] =
                *(const f16x8*)(xT + ((size_t)b * NPIX + (size_t)(nt * 128 + n)) * CHN + c0 + cg * 8);
        }
        __syncthreads();

        #pragma unroll
        for (int kk = 0; kk < 64; kk += 16) {
            const f16x8 bf = *(const f16x8*)&xs[wave * 32 + row][kk + lh * 8];
            #pragma unroll
            for (int cs = 0; cs < 4; ++cs) {
                const f16x8 af = *(const f16x8*)&wsm[cs * 32 + row][kk + lh * 8];
                acc[cs] = __builtin_amdgcn_mfma_f32_32x32x16_f16(af, bf, acc[cs], 0, 0, 0);
            }
        }
    }

    const int n = nt * 128 + wave * 32 + row;
    if (rt == 0) {
        #pragma unroll
        for (int cs = 0; cs < 4; ++cs)
            #pragma unroll
            for (int r = 0; r < 16; ++r) {
                const int i = cs * 32 + (r & 3) + 8 * (r >> 2) + 4 * lh;
                const f16 val = (f16)acc[cs][r];
                if (i < 64) qTo[((size_t)b * NPIX + n) * INTER + i] = val;
                else        kTo[((size_t)b * NPIX + n) * INTER + i - 64] = val;
            }
    } else {
        #pragma unroll
        for (int cs = 0; cs < 4; ++cs)
            #pragma unroll
            for (int r = 0; r < 16; ++r) {
                const int c = (rt - 1) * 128 + cs * 32 + (r & 3) + 8 * (r >> 2) + 4 * lh;
                vout[((size_t)b * CHN + c) * NPIX + n] = f2bf(acc[cs][r]);
            }
    }
}

// ---------------------------------------------------------------------------
// Attention v6: wave owns 32 n x ALL 128 c of the block -> every (n,m) logit
// exp'd exactly ONCE per block (R5 had 2x intra-block redundancy and with it
// 2x QK MFMA + 2x exp/pack/swap VALU). Block = 128 n x 128 c, 4 waves.
// Per 64-m tile (double-buffered LDS v+k, ONE barrier/iter):
//   - prefetch next v-tile (128c x 64m) + k-tile (64m x 64i) coalesced 16B,
//     chunk-XOR-swizzled LDS (<=2-way bank alias = free, per m136)
//   - QK^T for this wave's 32 n, both m-halves (8 MFMA, A=k LDS, B=q regs)
//   - exp (unnormalized; bf16 carries fp32 exponent) -> pack -> permlane32
//     swaps (HW-verified R4/R5) -> P[64m x 32n] as PV B-operands in-register
//   - PV: 4 c-strips x 4 m-chunks (16 MFMA, A=v LDS)
// grid (18 n-tiles, 4 c-quarters, 16 b) = 1152 blocks, block 256.
// launch_bounds(256,3): target 12 waves/CU (LDS 48KB allows 3 blocks/CU).
// ---------------------------------------------------------------------------
__global__ __launch_bounds__(256, 3) void attn_kernel(
    const float* __restrict__ x, const float* __restrict__ gamma,
    const f16* __restrict__ qT, const f16* __restrict__ kT,
    const unsigned short* __restrict__ vglob, float* __restrict__ out)
{
    const int nt = blockIdx.x;    // 128-n tile
    const int cq = blockIdx.y;    // 128-c quarter
    const int b  = blockIdx.z;
    const int t  = threadIdx.x;
    const int wave = t >> 6, lane = t & 63;
    const int row = lane & 31, lh = lane >> 5;

    __shared__ short vbuf[2][128 * 64];   // [buf][c][m] chunk-swizzled, 32 KB
    __shared__ f16   kbuf[2][64 * 64];    // [buf][m][i] chunk-swizzled, 16 KB

    const unsigned short* vq = vglob + ((size_t)b * CHN + (size_t)cq * 128) * NPIX;
    const f16* kb = kT + (size_t)b * NPIX * INTER;

    // staging ids (coalesced global: inner 8 chunks = one 128 B row)
    const int vcr = t >> 3;        // base v c-row (0..31), +32*j
    const int vmc = t & 7;         // m-chunk
    const int kmm = t >> 3;        // base k m-row
    const int kic = t & 7;         // i-chunk

    const int xorv = row & 7;      // fragment-read chunk swizzle

    // q fragments: resident (B operand; col n = lane&31); wave owns 32 n
    f16x8 qf[4];
    {
        const f16* qrow = qT + ((size_t)b * NPIX
                          + (size_t)(nt * 128 + wave * 32 + row)) * INTER + lh * 8;
        #pragma unroll
        for (int k0 = 0; k0 < 4; ++k0) qf[k0] = *(const f16x8*)(qrow + k0 * 16);
    }

    // ---- prologue: stage tile 0 into buf 0
    #pragma unroll
    for (int j = 0; j < 4; ++j) {
        const int cr = vcr + j * 32;
        const s16x8 g = *(const s16x8*)(vq + (size_t)cr * NPIX + vmc * 8);
        *(s16x8*)&vbuf[0][cr * 64 + ((vmc ^ (cr & 7)) * 8)] = g;
    }
    #pragma unroll
    for (int j = 0; j < 2; ++j) {
        const int mm = kmm + j * 32;
        const f16x8 g = *(const f16x8*)(kb + (size_t)mm * INTER + kic * 8);
        *(f16x8*)&kbuf[0][mm * 64 + ((kic ^ (mm & 7)) * 8)] = g;
    }
    __syncthreads();

    f32x16 accv[4];   // [cs] : (32 c) x (this wave's 32 n)
    #pragma unroll
    for (int s = 0; s < 4; ++s)
        #pragma unroll
        for (int r = 0; r < 16; ++r) accv[s][r] = 0.0f;

    float lrun = 0.0f;
    union PB { unsigned u[4]; s16x8 v; };

    for (int it = 0; it < NPIX / 64; ++it) {
        const int cur = it & 1, nxt = cur ^ 1;
        const int m1 = (it < NPIX / 64 - 1) ? (it + 1) * 64 : 0;  // last: dummy reload

        // ---- issue coalesced global loads for tile it+1 (latency spans QK+exp)
        s16x8 vg[4]; f16x8 kg[2];
        #pragma unroll
        for (int j = 0; j < 4; ++j)
            vg[j] = *(const s16x8*)(vq + (size_t)(vcr + j * 32) * NPIX + m1 + vmc * 8);
        #pragma unroll
        for (int j = 0; j < 2; ++j)
            kg[j] = *(const f16x8*)(kb + (size_t)(m1 + kmm + j * 32) * INTER + kic * 8);

        // ---- QK^T both m-halves for this wave's 32 n; exp + pack + transform
        PB pb[4];   // [kk] : P B-operand, m-chunk kk*16
        #pragma unroll
        for (int mh = 0; mh < 2; ++mh) {
            f32x16 sacc;
            #pragma unroll
            for (int r = 0; r < 16; ++r) sacc[r] = 0.0f;
            #pragma unroll
            for (int k0 = 0; k0 < 4; ++k0) {
                const f16x8 af = *(const f16x8*)&kbuf[cur][(mh * 32 + row) * 64
                                    + (((k0 * 2 + lh) ^ xorv) * 8)];
                sacc = __builtin_amdgcn_mfma_f32_32x32x16_f16(af, qf[k0], sacc, 0, 0, 0);
            }
            float lp = 0.0f;
            unsigned pg[8];
            #pragma unroll
            for (int tt = 0; tt < 8; ++tt) {
                const float p0 = __expf(sacc[2 * tt + 0]);
                const float p1 = __expf(sacc[2 * tt + 1]);
                lp += p0 + p1;
                pg[tt] = pack_bf16(p0, p1);
            }
            lrun += lp;
            #pragma unroll
            for (int half = 0; half < 2; ++half)
                #pragma unroll
                for (int p = 0; p < 2; ++p) {
                    unsigned nx, ny;
                    swap32(pg[half * 4 + p], pg[half * 4 + 2 + p], nx, ny, lh);
                    pb[2 * mh + half].u[p]     = nx;
                    pb[2 * mh + half].u[p + 2] = ny;
                }
        }

        // ---- write staged tile it+1 into alt buffers (vmcnt drains here)
        #pragma unroll
        for (int j = 0; j < 4; ++j) {
            const int cr = vcr + j * 32;
            *(s16x8*)&vbuf[nxt][cr * 64 + ((vmc ^ (cr & 7)) * 8)] = vg[j];
        }
        #pragma unroll
        for (int j = 0; j < 2; ++j) {
            const int mm = kmm + j * 32;
            *(f16x8*)&kbuf[nxt][mm * 64 + ((kic ^ (mm & 7)) * 8)] = kg[j];
        }

        // ---- PV: A = v-frags from LDS (full 128 c), B = pb regs
        #pragma unroll
        for (int cs = 0; cs < 4; ++cs)
            #pragma unroll
            for (int kk = 0; kk < 4; ++kk) {
                const s16x8 va = *(const s16x8*)&vbuf[cur][(cs * 32 + row) * 64
                                    + (((kk * 2 + lh) ^ xorv) * 8)];
                accv[cs] = __builtin_amdgcn_mfma_f32_32x32x16_bf16(
                    va, pb[kk].v, accv[cs], 0, 0, 0);
            }

        __syncthreads();   // cur-buf readers done; nxt-buf writes visible
    }

    // ---- epilogue: l combine (lane-half pair covers all 64 m), out = g*acc/l + x
    const float g = gamma[0];
    const float linv = 1.0f / (lrun + __shfl_xor(lrun, 32, 64));
    const int n = nt * 128 + wave * 32 + row;

    #pragma unroll
    for (int cs = 0; cs < 4; ++cs)
        #pragma unroll
        for (int r = 0; r < 16; ++r) {
            const int c = cq * 128 + cs * 32 + (r & 3) + 8 * (r >> 2) + 4 * lh;
            const size_t idx = ((size_t)b * CHN + c) * NPIX + n;
            out[idx] = g * accv[cs][r] * linv + x[idx];
        }
}

// ---------------------------------------------------------------------------
extern "C" void kernel_launch(void* const* d_in, const int* in_sizes, int n_in,
                              void* d_out, int out_size, void* d_ws, size_t ws_size,
                              hipStream_t stream) {
    (void)in_sizes; (void)n_in; (void)out_size; (void)ws_size;
    const float* x     = (const float*)d_in[0];
    const float* Wq    = (const float*)d_in[1];
    const float* Wk    = (const float*)d_in[2];
    const float* Wv    = (const float*)d_in[3];
    const float* gamma = (const float*)d_in[4];
    float* out = (float*)d_out;
    char* ws = (char*)d_ws;

    f16* xT  = (f16*)(ws + XT_OFF);
    f16* qTp = (f16*)(ws + QT_OFF);
    f16* kTp = (f16*)(ws + KT_OFF);
    unsigned short* vb = (unsigned short*)(ws + VB_OFF);
    f16* whq = (f16*)(ws + WHQ_OFF);
    f16* whk = (f16*)(ws + WHK_OFF);
    f16* whv = (f16*)(ws + WHV_OFF);

    convert_x_kernel<<<dim3(36, 8, 16), 256, 0, stream>>>(x, xT);
    convert_w_kernel<<<dim3(256, 3, 1), 256, 0, stream>>>(Wq, Wk, Wv, whq, whk, whv);
    proj_kernel<<<dim3(18, 5, 16), 256, 0, stream>>>(xT, whq, whk, whv, qTp, kTp, vb);
    attn_kernel<<<dim3(18, 4, 16), 256, 0, stream>>>(x, gamma, qTp, kTp, vb, out);
}